// Round 2
// baseline (319.515 us; speedup 1.0000x reference)
//
#include <hip/hip_runtime.h>
#include <hip/hip_bf16.h>

#define S_LEN 2048
#define NB 2
#define NH 16
#define DH 128
#define ROW_STRIDE (NB * NH * DH)   // 4096 floats between consecutive s
#define M_TILE 128                  // q rows per block
#define N_TILE 64                   // k rows per tile
#define NKT (S_LEN / N_TILE)        // 32

typedef __bf16 bf16x8_t __attribute__((ext_vector_type(8)));
typedef __bf16 bf16x4_t __attribute__((ext_vector_type(4)));
typedef float  f32x4_t  __attribute__((ext_vector_type(4)));

#define LDS_KS 136   // K tile row stride (elements): 272B rows, 16B aligned
#define LDS_VS 68    // V^T tile row stride: 136B rows, 8B aligned (b64 reads)
#define LDS_PS 68    // P tile row stride (per wave)

#if defined(__has_builtin)
#if __has_builtin(__builtin_amdgcn_exp2f)
#define EXP2F __builtin_amdgcn_exp2f
#else
#define EXP2F exp2f
#endif
#else
#define EXP2F exp2f
#endif

__global__ __launch_bounds__(256, 2) void fa_kernel(
    const float* __restrict__ Qg, const float* __restrict__ Kg,
    const float* __restrict__ Vg, const int* __restrict__ Mg,
    float* __restrict__ Og)
{
    __shared__ __bf16 kT[64 * LDS_KS];       // K tile  [t][d]
    __shared__ __bf16 vT[DH * LDS_VS];       // V tile  [d][t] (transposed)
    __shared__ __bf16 pT[4 * 32 * LDS_PS];   // P tile, wave-private [32 rows][64 t]

    const int tid  = threadIdx.x;
    const int wave = tid >> 6;
    const int lane = tid & 63;
    const int l15  = lane & 15;
    const int quad = lane >> 4;

    const int bid = blockIdx.x;
    const int qt  = bid & 15;       // q-tile index (S/M_TILE = 16)
    const int bh  = bid >> 4;
    const int h   = bh & (NH - 1);
    const int b   = bh >> 4;

    const int q0       = qt * M_TILE;
    const int head_off = b * (NH * DH) + h * DH;

    // softmax in exp2 domain: scale = log2(e)/sqrt(128); mask -> -10000*log2(e)
    const float kScale   = 1.44269504088896340736f / 11.31370849898476039f;
    const float kMaskVal = -14426.950408889634f;

    // ---- Q fragments (A-layout: m = l15, k(d) = kc*32 + quad*8 + j) ----
    bf16x8_t qf[2][4];
#pragma unroll
    for (int mt = 0; mt < 2; ++mt) {
        const int srow = q0 + wave * 32 + mt * 16 + l15;
        const float* qp = Qg + (size_t)srow * ROW_STRIDE + head_off + quad * 8;
#pragma unroll
        for (int kc = 0; kc < 4; ++kc) {
            float4 f0 = *(const float4*)(qp + kc * 32);
            float4 f1 = *(const float4*)(qp + kc * 32 + 4);
            bf16x8_t v;
            v[0] = (__bf16)f0.x; v[1] = (__bf16)f0.y;
            v[2] = (__bf16)f0.z; v[3] = (__bf16)f0.w;
            v[4] = (__bf16)f1.x; v[5] = (__bf16)f1.y;
            v[6] = (__bf16)f1.z; v[7] = (__bf16)f1.w;
            qf[mt][kc] = v;
        }
    }

    f32x4_t oacc[2][8];              // O accum, C-layout: [mt][dt], col=l15, row=quad*4+r
    float mstate[2][4], lstate[2][4];
#pragma unroll
    for (int mt = 0; mt < 2; ++mt) {
#pragma unroll
        for (int dt = 0; dt < 8; ++dt) oacc[mt][dt] = {0.0f, 0.0f, 0.0f, 0.0f};
#pragma unroll
        for (int r = 0; r < 4; ++r) { mstate[mt][r] = -3.0e38f; lstate[mt][r] = 0.0f; }
    }

    __bf16* pW = &pT[wave * 32 * LDS_PS];

    for (int kt = 0; kt < NKT; ++kt) {
        const int t0 = kt * N_TILE;
        __syncthreads();   // previous tile's kT/vT reads complete

        // ---- stage K tile: kT[t][d], coalesced float4 rows ----
        {
            const int r0 = tid >> 5;           // 0..7
            const int c4 = (tid & 31) * 4;     // 0..124
            const float* kp = Kg + (size_t)(t0 + r0) * ROW_STRIDE + head_off + c4;
            __bf16* kd = &kT[r0 * LDS_KS + c4];
#pragma unroll
            for (int rr = 0; rr < 8; ++rr) {
                float4 f = *(const float4*)kp;
                bf16x4_t w;
                w[0] = (__bf16)f.x; w[1] = (__bf16)f.y;
                w[2] = (__bf16)f.z; w[3] = (__bf16)f.w;
                *(bf16x4_t*)kd = w;
                kp += 8 * ROW_STRIDE;
                kd += 8 * LDS_KS;
            }
        }
        // ---- stage V tile transposed: vT[d][t]; dword loads stay coalesced,
        //      scatter b16 writes hit banks 2d mod 32 -> ~2-way (free) ----
        {
            const int tv = tid >> 5;           // 0..7
            const int dv = tid & 31;
            const float* vp = Vg + (size_t)(t0 + tv) * ROW_STRIDE + head_off + dv;
#pragma unroll
            for (int rr = 0; rr < 8; ++rr) {
                const float* vpp = vp + (size_t)rr * 8 * ROW_STRIDE;
                const int trow = tv + rr * 8;
#pragma unroll
                for (int j = 0; j < 4; ++j)
                    vT[(dv + j * 32) * LDS_VS + trow] = (__bf16)vpp[j * 32];
            }
        }
        __syncthreads();

        // ---- S = Q K^T (C-layout), b128 B-frag reads from kT ----
        f32x4_t sacc[2][4];
#pragma unroll
        for (int mt = 0; mt < 2; ++mt)
#pragma unroll
            for (int n = 0; n < 4; ++n) sacc[mt][n] = {0.0f, 0.0f, 0.0f, 0.0f};
#pragma unroll
        for (int n = 0; n < 4; ++n) {
#pragma unroll
            for (int kc = 0; kc < 4; ++kc) {
                bf16x8_t kb = *(const bf16x8_t*)&kT[(n * 16 + l15) * LDS_KS + kc * 32 + quad * 8];
                sacc[0][n] = __builtin_amdgcn_mfma_f32_16x16x32_bf16(qf[0][kc], kb, sacc[0][n], 0, 0, 0);
                sacc[1][n] = __builtin_amdgcn_mfma_f32_16x16x32_bf16(qf[1][kc], kb, sacc[1][n], 0, 0, 0);
            }
        }

        // ---- mask + online softmax + P -> LDS (C-layout -> A-layout round trip) ----
#pragma unroll
        for (int mt = 0; mt < 2; ++mt) {
            const int mrow0 = q0 + wave * 32 + mt * 16 + quad * 4;
            const int* mp =
                Mg + (size_t)b * S_LEN * S_LEN + (size_t)mrow0 * S_LEN + t0 + l15;
            float sv[4][4];
#pragma unroll
            for (int n = 0; n < 4; ++n)
#pragma unroll
                for (int r = 0; r < 4; ++r) {
                    float s = sacc[mt][n][r] * kScale;
                    sv[n][r] = mp[(size_t)r * S_LEN + n * 16] ? kMaskVal : s;
                }
#pragma unroll
            for (int r = 0; r < 4; ++r) {
                float tm = fmaxf(fmaxf(sv[0][r], sv[1][r]), fmaxf(sv[2][r], sv[3][r]));
                tm = fmaxf(tm, __shfl_xor(tm, 1, 64));
                tm = fmaxf(tm, __shfl_xor(tm, 2, 64));
                tm = fmaxf(tm, __shfl_xor(tm, 4, 64));
                tm = fmaxf(tm, __shfl_xor(tm, 8, 64));
                const float mold  = mstate[mt][r];
                const float mnew  = fmaxf(mold, tm);
                const float alpha = EXP2F(mold - mnew);
                float rsum = 0.0f;
#pragma unroll
                for (int n = 0; n < 4; ++n) {
                    float p = EXP2F(sv[n][r] - mnew);
                    rsum += p;
                    pW[(mt * 16 + quad * 4 + r) * LDS_PS + n * 16 + l15] = (__bf16)p;
                }
                rsum += __shfl_xor(rsum, 1, 64);
                rsum += __shfl_xor(rsum, 2, 64);
                rsum += __shfl_xor(rsum, 4, 64);
                rsum += __shfl_xor(rsum, 8, 64);
                lstate[mt][r] = lstate[mt][r] * alpha + rsum;
                mstate[mt][r] = mnew;
#pragma unroll
                for (int dt = 0; dt < 8; ++dt) oacc[mt][dt][r] *= alpha;
            }
        }

        // ---- O += P V : A-frag from pW, B-frag from vT (b64 pairs) ----
#pragma unroll
        for (int kc2 = 0; kc2 < 2; ++kc2) {
            bf16x8_t af[2];
#pragma unroll
            for (int mt = 0; mt < 2; ++mt) {
                bf16x4_t lo = *(const bf16x4_t*)&pW[(mt * 16 + l15) * LDS_PS + kc2 * 32 + quad * 8];
                bf16x4_t hi = *(const bf16x4_t*)&pW[(mt * 16 + l15) * LDS_PS + kc2 * 32 + quad * 8 + 4];
                af[mt] = __builtin_shufflevector(lo, hi, 0, 1, 2, 3, 4, 5, 6, 7);
            }
#pragma unroll
            for (int dt = 0; dt < 8; ++dt) {
                bf16x4_t v0 = *(const bf16x4_t*)&vT[(dt * 16 + l15) * LDS_VS + kc2 * 32 + quad * 8];
                bf16x4_t v1 = *(const bf16x4_t*)&vT[(dt * 16 + l15) * LDS_VS + kc2 * 32 + quad * 8 + 4];
                bf16x8_t bfr = __builtin_shufflevector(v0, v1, 0, 1, 2, 3, 4, 5, 6, 7);
                oacc[0][dt] = __builtin_amdgcn_mfma_f32_16x16x32_bf16(af[0], bfr, oacc[0][dt], 0, 0, 0);
                oacc[1][dt] = __builtin_amdgcn_mfma_f32_16x16x32_bf16(af[1], bfr, oacc[1][dt], 0, 0, 0);
            }
        }
    }

    // ---- epilogue: O / l, C-layout scatter (64B segments per quad) ----
#pragma unroll
    for (int mt = 0; mt < 2; ++mt) {
#pragma unroll
        for (int r = 0; r < 4; ++r) {
            const float inv = 1.0f / lstate[mt][r];
            const int srow = q0 + wave * 32 + mt * 16 + quad * 4 + r;
            float* op = Og + (size_t)srow * ROW_STRIDE + head_off + l15;
#pragma unroll
            for (int dt = 0; dt < 8; ++dt) op[dt * 16] = oacc[mt][dt][r] * inv;
        }
    }
}

extern "C" void kernel_launch(void* const* d_in, const int* in_sizes, int n_in,
                              void* d_out, int out_size, void* d_ws, size_t ws_size,
                              hipStream_t stream) {
    (void)in_sizes; (void)n_in; (void)d_ws; (void)ws_size; (void)out_size;
    const float* Q = (const float*)d_in[0];
    const float* K = (const float*)d_in[1];
    const float* V = (const float*)d_in[2];
    const int*   M = (const int*)d_in[3];
    float* O = (float*)d_out;
    dim3 grid(NB * NH * (S_LEN / M_TILE));   // 512 blocks = 2/CU
    dim3 block(256);
    hipLaunchKernelGGL(fa_kernel, grid, block, 0, stream, Q, K, V, M, O);
}